// Round 2
// baseline (923.236 us; speedup 1.0000x reference)
//
#include <hip/hip_runtime.h>
#include <math.h>

#define D_ 768
#define H_ 3072
#define L_ 256
#define NM_ 256
#define EPS_ 1e-5f
#define SCALE_ 0.036084391824351615f  // 1/sqrt(768)

__device__ __forceinline__ float wave_sum(float v) {
#pragma unroll
  for (int o = 32; o; o >>= 1) v += __shfl_down(v, o);
  return v;
}

// ---------------- transpose (32x32 tiles, 256 threads) ----------------
__global__ __launch_bounds__(256) void k_transpose(const float* __restrict__ src,
                                                   float* __restrict__ dst, int R, int C) {
  __shared__ float tile[32][33];
  int bx = blockIdx.x * 32, by = blockIdx.y * 32;
  int tx = threadIdx.x & 31, ty = threadIdx.x >> 5;  // ty 0..7
#pragma unroll
  for (int i = ty; i < 32; i += 8) tile[i][tx] = src[(size_t)(by + i) * C + bx + tx];
  __syncthreads();
#pragma unroll
  for (int i = ty; i < 32; i += 8) dst[(size_t)(bx + i) * R + by + tx] = tile[tx][i];
}

// ---------------- q = probe @ wq.T + bq ----------------
__global__ __launch_bounds__(256) void k_qproj(const float* __restrict__ probe,
                                               const float* __restrict__ wq,
                                               const float* __restrict__ bq,
                                               float* __restrict__ q_out) {
  __shared__ float pr[D_];
  int t = threadIdx.x;
  for (int i = t; i < D_; i += 256) pr[i] = probe[i];
  __syncthreads();
  int wave = t >> 6, lane = t & 63;
  int row0 = blockIdx.x * 64 + wave * 16;
  for (int rr = 0; rr < 16; ++rr) {
    int row = row0 + rr;
    const float4* wrow = (const float4*)(wq + (size_t)row * D_);
    const float4* prow = (const float4*)pr;
    float acc = 0.f;
#pragma unroll
    for (int it = 0; it < 3; ++it) {
      float4 w4 = wrow[it * 64 + lane];
      float4 p4 = prow[it * 64 + lane];
      acc += w4.x * p4.x + w4.y * p4.y + w4.z * p4.z + w4.w * p4.w;
    }
    acc = wave_sum(acc);
    if (lane == 0) q_out[row] = acc + bq[row];
  }
}

// ---------------- qk[d] = scale * sum_j q[j]*wk[j,d]; bias = scale * q.bk ----------------
__global__ __launch_bounds__(256) void k_kproj(const float* __restrict__ q,
                                               const float* __restrict__ wk,
                                               const float* __restrict__ bk,
                                               float* __restrict__ qk,
                                               float* __restrict__ bias) {
  __shared__ float qs[D_];
  __shared__ float red[256];
  int t = threadIdx.x;
  for (int i = t; i < D_; i += 256) qs[i] = q[i];
  __syncthreads();
  int d = blockIdx.x * 256 + t;
  float acc = 0.f;
  for (int j = 0; j < D_; ++j) acc += qs[j] * wk[(size_t)j * D_ + d];
  qk[d] = acc * SCALE_;
  if (blockIdx.x == 0) {
    float s = 0.f;
    for (int j = t; j < D_; j += 256) s += qs[j] * bk[j];
    red[t] = s;
    __syncthreads();
    for (int o = 128; o; o >>= 1) {
      if (t < o) red[t] += red[t + o];
      __syncthreads();
    }
    if (t == 0) bias[0] = red[0] * SCALE_;
  }
}

// ---------------- online-softmax attention pooling ----------------
// one block per (n,m); single pass over x; pooled[nm][d] = sum_l softmax_l * x[l,d]
#define CHUNK_ 16
__global__ __launch_bounds__(256) void k_attnpool(const float* __restrict__ x,
                                                  const float* __restrict__ qk,
                                                  const float* __restrict__ bias,
                                                  float* __restrict__ pooled) {
  __shared__ float xs[CHUNK_][D_];     // 48 KB
  __shared__ float qk_s[D_];           // 3 KB
  __shared__ float sc_s[CHUNK_];
  __shared__ float red[4][D_];         // 12 KB
  int t = threadIdx.x, wave = t >> 6, lane = t & 63;
  int nm = blockIdx.x;
  const float* xb = x + (size_t)nm * L_ * D_;
  for (int i = t; i < D_; i += 256) qk_s[i] = qk[i];
  float ab = bias[0];

  float m_run = -1e30f, l_run = 0.f;
  float acc[3][4];
#pragma unroll
  for (int it = 0; it < 3; ++it)
#pragma unroll
    for (int c = 0; c < 4; ++c) acc[it][c] = 0.f;

  const float4* qk4 = (const float4*)qk_s;

  for (int ch = 0; ch < L_ / CHUNK_; ++ch) {
    __syncthreads();  // xs free
    // stage chunk: CHUNK_*768 floats, coalesced float4
    {
      const float4* src = (const float4*)(xb + (size_t)ch * CHUNK_ * D_);
      float4* dstv = (float4*)&xs[0][0];
      for (int i = t; i < CHUNK_ * (D_ / 4); i += 256) dstv[i] = src[i];
    }
    __syncthreads();  // xs ready
    // scores: wave w handles rows 4w..4w+3
#pragma unroll
    for (int q = 0; q < 4; ++q) {
      int rr = 4 * wave + q;
      const float4* xr = (const float4*)&xs[rr][0];
      float a = 0.f;
#pragma unroll
      for (int it = 0; it < 3; ++it) {
        float4 xv = xr[it * 64 + lane];
        float4 qv = qk4[it * 64 + lane];
        a += xv.x * qv.x + xv.y * qv.y + xv.z * qv.z + xv.w * qv.w;
      }
      a = wave_sum(a);
      if (lane == 0) sc_s[rr] = a + ab;
    }
    __syncthreads();  // scores ready
    // online softmax update (uniform across all threads)
    float mx = m_run;
#pragma unroll
    for (int i = 0; i < CHUNK_; ++i) mx = fmaxf(mx, sc_s[i]);
    float factor = expf(m_run - mx);
    float psum = 0.f;
#pragma unroll
    for (int i = 0; i < CHUNK_; ++i) psum += expf(sc_s[i] - mx);
    l_run = l_run * factor + psum;
    m_run = mx;
#pragma unroll
    for (int it = 0; it < 3; ++it)
#pragma unroll
      for (int c = 0; c < 4; ++c) acc[it][c] *= factor;
    // accumulate: wave w owns rows 4w..4w+3
#pragma unroll
    for (int q = 0; q < 4; ++q) {
      int rr = 4 * wave + q;
      float pq = expf(sc_s[rr] - mx);
      const float4* xr = (const float4*)&xs[rr][0];
#pragma unroll
      for (int it = 0; it < 3; ++it) {
        float4 xv = xr[it * 64 + lane];
        acc[it][0] += pq * xv.x;
        acc[it][1] += pq * xv.y;
        acc[it][2] += pq * xv.z;
        acc[it][3] += pq * xv.w;
      }
    }
  }
  // cross-wave reduce
#pragma unroll
  for (int it = 0; it < 3; ++it) {
    float4 v = make_float4(acc[it][0], acc[it][1], acc[it][2], acc[it][3]);
    *(float4*)&red[wave][it * 256 + 4 * lane] = v;
  }
  __syncthreads();
  float inv = 1.f / l_run;
#pragma unroll
  for (int it = 0; it < 3; ++it) {
    int dd = t + it * 256;
    pooled[(size_t)nm * D_ + dd] = (red[0][dd] + red[1][dd] + red[2][dd] + red[3][dd]) * inv;
  }
}

// ---------------- xo = pooled @ wv.T + bv ; y = LN(xo) ----------------
// 4 rows per block, 64 blocks; thread t owns cols t, t+256, t+512
__global__ __launch_bounds__(256) void k_xo_ln(const float* __restrict__ pooled,
                                               const float* __restrict__ wvT,
                                               const float* __restrict__ bv,
                                               const float* __restrict__ gamma,
                                               const float* __restrict__ beta,
                                               float* __restrict__ xo,
                                               float* __restrict__ y) {
  __shared__ float a_s[4][D_];  // 12 KB
  __shared__ float tmpa[4], tmpb[4];
  int t = threadIdx.x, wave = t >> 6, lane = t & 63;
  int r0 = blockIdx.x * 4;
  for (int i = t; i < 4 * D_; i += 256) (&a_s[0][0])[i] = pooled[(size_t)r0 * D_ + i];
  __syncthreads();
  float acc[4][3];
#pragma unroll
  for (int cc = 0; cc < 3; ++cc) {
    float b = bv[t + 256 * cc];
#pragma unroll
    for (int r = 0; r < 4; ++r) acc[r][cc] = b;
  }
  for (int k = 0; k < D_; k += 4) {
    float4 av[4];
#pragma unroll
    for (int r = 0; r < 4; ++r) av[r] = *(const float4*)&a_s[r][k];
#pragma unroll
    for (int u = 0; u < 4; ++u) {
      const float* wrow = wvT + (size_t)(k + u) * D_ + t;
      float w0 = wrow[0], w1_ = wrow[256], w2_ = wrow[512];
#pragma unroll
      for (int r = 0; r < 4; ++r) {
        float a = ((const float*)&av[r])[u];
        acc[r][0] += a * w0;
        acc[r][1] += a * w1_;
        acc[r][2] += a * w2_;
      }
    }
  }
  for (int r = 0; r < 4; ++r) {
    float s = acc[r][0] + acc[r][1] + acc[r][2];
    float ss = acc[r][0] * acc[r][0] + acc[r][1] * acc[r][1] + acc[r][2] * acc[r][2];
#pragma unroll
    for (int o = 32; o; o >>= 1) {
      s += __shfl_down(s, o);
      ss += __shfl_down(ss, o);
    }
    if (lane == 0) { tmpa[wave] = s; tmpb[wave] = ss; }
    __syncthreads();
    float mu = (tmpa[0] + tmpa[1] + tmpa[2] + tmpa[3]) * (1.f / D_);
    float var = (tmpb[0] + tmpb[1] + tmpb[2] + tmpb[3]) * (1.f / D_) - mu * mu;
    float rs = rsqrtf(var + EPS_);
    __syncthreads();
    int row = r0 + r;
#pragma unroll
    for (int cc = 0; cc < 3; ++cc) {
      int j = t + 256 * cc;
      float v = acc[r][cc];
      xo[(size_t)row * D_ + j] = v;
      y[(size_t)row * D_ + j] = (v - mu) * rs * gamma[j] + beta[j];
    }
  }
}

// ---------------- h = gelu(y @ w1.T + b1) ----------------
// 8 rows x 768-col tile; grid (32, 4)
__global__ __launch_bounds__(256) void k_mlp1(const float* __restrict__ y,
                                              const float* __restrict__ w1T,
                                              const float* __restrict__ b1,
                                              float* __restrict__ h) {
  __shared__ float a_s[8][D_];  // 24 KB
  int t = threadIdx.x;
  int r0 = blockIdx.x * 8;
  int jbase = blockIdx.y * 768 + t;
  for (int i = t; i < 8 * D_; i += 256) (&a_s[0][0])[i] = y[(size_t)r0 * D_ + i];
  __syncthreads();
  float acc[8][3];
#pragma unroll
  for (int cc = 0; cc < 3; ++cc) {
    float b = b1[jbase + 256 * cc];
#pragma unroll
    for (int r = 0; r < 8; ++r) acc[r][cc] = b;
  }
  for (int k = 0; k < D_; k += 4) {
    float4 av[8];
#pragma unroll
    for (int r = 0; r < 8; ++r) av[r] = *(const float4*)&a_s[r][k];
#pragma unroll
    for (int u = 0; u < 4; ++u) {
      const float* wrow = w1T + (size_t)(k + u) * H_ + jbase;
      float w0 = wrow[0], w1_ = wrow[256], w2_ = wrow[512];
#pragma unroll
      for (int r = 0; r < 8; ++r) {
        float a = ((const float*)&av[r])[u];
        acc[r][0] += a * w0;
        acc[r][1] += a * w1_;
        acc[r][2] += a * w2_;
      }
    }
  }
  for (int r = 0; r < 8; ++r) {
#pragma unroll
    for (int cc = 0; cc < 3; ++cc) {
      float v = acc[r][cc];
      float g = 0.5f * v * (1.f + erff(v * 0.70710678118f));
      h[(size_t)(r0 + r) * H_ + jbase + 256 * cc] = g;
    }
  }
}

// ---------------- out = xo + h @ w2.T + b2 ----------------
// 8 rows x 256-col tile; grid (32, 3); K=3072 staged in 4 chunks of 768
__global__ __launch_bounds__(256) void k_mlp2(const float* __restrict__ h,
                                              const float* __restrict__ w2T,
                                              const float* __restrict__ b2,
                                              const float* __restrict__ xo,
                                              float* __restrict__ out) {
  __shared__ float h_s[8][768];  // 24 KB
  int t = threadIdx.x;
  int r0 = blockIdx.x * 8;
  int j = blockIdx.y * 256 + t;
  float acc[8];
#pragma unroll
  for (int r = 0; r < 8; ++r) acc[r] = 0.f;
  for (int c = 0; c < 4; ++c) {
    __syncthreads();
    for (int i = t; i < 8 * 768; i += 256) {
      int rr = i / 768, kk = i % 768;
      h_s[rr][kk] = h[(size_t)(r0 + rr) * H_ + c * 768 + kk];
    }
    __syncthreads();
    for (int kk = 0; kk < 768; kk += 4) {
      float4 hv[8];
#pragma unroll
      for (int r = 0; r < 8; ++r) hv[r] = *(const float4*)&h_s[r][kk];
#pragma unroll
      for (int u = 0; u < 4; ++u) {
        float w = w2T[(size_t)(c * 768 + kk + u) * D_ + j];
#pragma unroll
        for (int r = 0; r < 8; ++r) acc[r] += ((const float*)&hv[r])[u] * w;
      }
    }
  }
  float bb = b2[j];
#pragma unroll
  for (int r = 0; r < 8; ++r)
    out[(size_t)(r0 + r) * D_ + j] = acc[r] + bb + xo[(size_t)(r0 + r) * D_ + j];
}

extern "C" void kernel_launch(void* const* d_in, const int* in_sizes, int n_in,
                              void* d_out, int out_size, void* d_ws, size_t ws_size,
                              hipStream_t stream) {
  const float* x = (const float*)d_in[0];
  const float* probe = (const float*)d_in[1];
  const float* wq = (const float*)d_in[2];
  const float* bq = (const float*)d_in[3];
  const float* wk = (const float*)d_in[4];
  const float* bk = (const float*)d_in[5];
  const float* wv = (const float*)d_in[6];
  const float* bv = (const float*)d_in[7];
  const float* gamma = (const float*)d_in[8];
  const float* beta = (const float*)d_in[9];
  const float* w1 = (const float*)d_in[10];
  const float* b1 = (const float*)d_in[11];
  const float* w2 = (const float*)d_in[12];
  const float* b2 = (const float*)d_in[13];
  float* out = (float*)d_out;

  float* ws = (float*)d_ws;
  float* qk = ws;                    // 768
  float* bias = ws + 768;            // 1
  float* q = ws + 1024;              // 768
  float* wvT = ws + 2048;            // 768*768
  float* w1T = wvT + 768 * 768;      // 768*3072
  float* w2T = w1T + 768 * 3072;     // 3072*768
  float* pooled = w2T + 3072 * 768;  // 256*768
  float* xo = pooled + NM_ * D_;     // 256*768
  float* y = xo + NM_ * D_;          // 256*768
  float* h = y + NM_ * D_;           // 256*3072

  hipLaunchKernelGGL(k_transpose, dim3(24, 24), dim3(256), 0, stream, wv, wvT, 768, 768);
  hipLaunchKernelGGL(k_transpose, dim3(24, 96), dim3(256), 0, stream, w1, w1T, 3072, 768);
  hipLaunchKernelGGL(k_transpose, dim3(96, 24), dim3(256), 0, stream, w2, w2T, 768, 3072);
  hipLaunchKernelGGL(k_qproj, dim3(12), dim3(256), 0, stream, probe, wq, bq, q);
  hipLaunchKernelGGL(k_kproj, dim3(3), dim3(256), 0, stream, q, wk, bk, qk, bias);
  hipLaunchKernelGGL(k_attnpool, dim3(NM_), dim3(256), 0, stream, x, qk, bias, pooled);
  hipLaunchKernelGGL(k_xo_ln, dim3(64), dim3(256), 0, stream, pooled, wvT, bv, gamma, beta, xo, y);
  hipLaunchKernelGGL(k_mlp1, dim3(32, 4), dim3(256), 0, stream, y, w1T, b1, h);
  hipLaunchKernelGGL(k_mlp2, dim3(32, 3), dim3(256), 0, stream, h, w2T, b2, xo, out);
}

// Round 3
// 441.712 us; speedup vs baseline: 2.0901x; 2.0901x over previous
//
#include <hip/hip_runtime.h>
#include <math.h>

#define D_ 768
#define H_ 3072
#define L_ 256
#define NM_ 256
#define EPS_ 1e-5f
#define SCALE_ 0.036084391824351615f  // 1/sqrt(768)

__device__ __forceinline__ float wave_sum(float v) {
#pragma unroll
  for (int o = 32; o; o >>= 1) v += __shfl_down(v, o);
  return v;
}

// ---------------- q = (probe @ wq.T + bq) * SCALE ----------------
__global__ __launch_bounds__(256) void k_qproj(const float* __restrict__ probe,
                                               const float* __restrict__ wq,
                                               const float* __restrict__ bq,
                                               float* __restrict__ q_out) {
  __shared__ float pr[D_];
  int t = threadIdx.x;
  for (int i = t; i < D_; i += 256) pr[i] = probe[i];
  __syncthreads();
  int wave = t >> 6, lane = t & 63;
  int row0 = blockIdx.x * 64 + wave * 16;
  for (int rr = 0; rr < 16; ++rr) {
    int row = row0 + rr;
    const float4* wrow = (const float4*)(wq + (size_t)row * D_);
    const float4* prow = (const float4*)pr;
    float acc = 0.f;
#pragma unroll
    for (int it = 0; it < 3; ++it) {
      float4 w4 = wrow[it * 64 + lane];
      float4 p4 = prow[it * 64 + lane];
      acc += w4.x * p4.x + w4.y * p4.y + w4.z * p4.z + w4.w * p4.w;
    }
    acc = wave_sum(acc);
    if (lane == 0) q_out[row] = (acc + bq[row]) * SCALE_;
  }
}

// ---------------- qkp[ks][d] = sum_{j in ks-range} q[j]*wk[j,d]; biasp[ks] ----------------
// grid (3 col-blocks, 4 k-split)
__global__ __launch_bounds__(256) void k_kproj(const float* __restrict__ q,
                                               const float* __restrict__ wk,
                                               const float* __restrict__ bk,
                                               float* __restrict__ qkp,
                                               float* __restrict__ biasp) {
  __shared__ float qs[192];
  __shared__ float red[256];
  int t = threadIdx.x;
  int c = blockIdx.x, ks = blockIdx.y;
  int jbase = 192 * ks;
  if (t < 192) qs[t] = q[jbase + t];
  __syncthreads();
  int d = c * 256 + t;
  float acc = 0.f;
  for (int jj = 0; jj < 192; ++jj) acc += qs[jj] * wk[(size_t)(jbase + jj) * D_ + d];
  qkp[ks * D_ + d] = acc;
  if (c == 0) {
    float s = (t < 192) ? qs[t] * bk[jbase + t] : 0.f;
    red[t] = s;
    __syncthreads();
    for (int o = 128; o; o >>= 1) {
      if (t < o) red[t] += red[t + o];
      __syncthreads();
    }
    if (t == 0) biasp[ks] = red[0];
  }
}

// ---------------- online-softmax attention pooling (L split in 2) ----------------
// grid (256 nm, 2 part); pooledP[part][nm][d] unnormalized; mlP[part][nm]=(m,l)
#define CHUNK_ 16
__global__ __launch_bounds__(256) void k_attnpool(const float* __restrict__ x,
                                                  const float* __restrict__ qkp,
                                                  const float* __restrict__ biasp,
                                                  float* __restrict__ pooledP,
                                                  float2* __restrict__ mlP) {
  __shared__ float xs[CHUNK_][D_];     // 48 KB
  __shared__ float qk_s[D_];           // 3 KB
  __shared__ float sc_s[CHUNK_];
  __shared__ float red[4][D_];         // 12 KB
  int t = threadIdx.x, wave = t >> 6, lane = t & 63;
  int nm = blockIdx.x, part = blockIdx.y;
  const float* xb = x + (size_t)nm * L_ * D_ + (size_t)part * (L_ / 2) * D_;
  for (int i = t; i < D_; i += 256)
    qk_s[i] = qkp[i] + qkp[D_ + i] + qkp[2 * D_ + i] + qkp[3 * D_ + i];
  float ab = biasp[0] + biasp[1] + biasp[2] + biasp[3];

  float m_run = -1e30f, l_run = 0.f;
  float acc[3][4];
#pragma unroll
  for (int it = 0; it < 3; ++it)
#pragma unroll
    for (int c = 0; c < 4; ++c) acc[it][c] = 0.f;

  const float4* qk4 = (const float4*)qk_s;

  for (int ch = 0; ch < (L_ / 2) / CHUNK_; ++ch) {
    __syncthreads();
    {
      const float4* src = (const float4*)(xb + (size_t)ch * CHUNK_ * D_);
      float4* dstv = (float4*)&xs[0][0];
      for (int i = t; i < CHUNK_ * (D_ / 4); i += 256) dstv[i] = src[i];
    }
    __syncthreads();
#pragma unroll
    for (int qq = 0; qq < 4; ++qq) {
      int rr = 4 * wave + qq;
      const float4* xr = (const float4*)&xs[rr][0];
      float a = 0.f;
#pragma unroll
      for (int it = 0; it < 3; ++it) {
        float4 xv = xr[it * 64 + lane];
        float4 qv = qk4[it * 64 + lane];
        a += xv.x * qv.x + xv.y * qv.y + xv.z * qv.z + xv.w * qv.w;
      }
      a = wave_sum(a);
      if (lane == 0) sc_s[rr] = a + ab;
    }
    __syncthreads();
    float mx = m_run;
#pragma unroll
    for (int i = 0; i < CHUNK_; ++i) mx = fmaxf(mx, sc_s[i]);
    float factor = expf(m_run - mx);
    float psum = 0.f;
#pragma unroll
    for (int i = 0; i < CHUNK_; ++i) psum += expf(sc_s[i] - mx);
    l_run = l_run * factor + psum;
    m_run = mx;
#pragma unroll
    for (int it = 0; it < 3; ++it)
#pragma unroll
      for (int c = 0; c < 4; ++c) acc[it][c] *= factor;
#pragma unroll
    for (int qq = 0; qq < 4; ++qq) {
      int rr = 4 * wave + qq;
      float pq = expf(sc_s[rr] - mx);
      const float4* xr = (const float4*)&xs[rr][0];
#pragma unroll
      for (int it = 0; it < 3; ++it) {
        float4 xv = xr[it * 64 + lane];
        acc[it][0] += pq * xv.x;
        acc[it][1] += pq * xv.y;
        acc[it][2] += pq * xv.z;
        acc[it][3] += pq * xv.w;
      }
    }
  }
#pragma unroll
  for (int it = 0; it < 3; ++it) {
    float4 v = make_float4(acc[it][0], acc[it][1], acc[it][2], acc[it][3]);
    *(float4*)&red[wave][it * 256 + 4 * lane] = v;
  }
  __syncthreads();
#pragma unroll
  for (int it = 0; it < 3; ++it) {
    int dd = t + it * 256;
    pooledP[((size_t)part * NM_ + nm) * D_ + dd] =
        red[0][dd] + red[1][dd] + red[2][dd] + red[3][dd];
  }
  if (t == 0) mlP[part * NM_ + nm] = make_float2(m_run, l_run);
}

// ---------------- merge two softmax parts (in-place into part 0) ----------------
__global__ __launch_bounds__(256) void k_merge(float* __restrict__ pooledP,
                                               const float2* __restrict__ mlP) {
  int t = threadIdx.x, nm = blockIdx.x;
  float2 a = mlP[nm], b = mlP[NM_ + nm];
  float M = fmaxf(a.x, b.x);
  float wa = expf(a.x - M), wb = expf(b.x - M);
  float inv = 1.f / (wa * a.y + wb * b.y);
#pragma unroll
  for (int it = 0; it < 3; ++it) {
    int d = t + it * 256;
    size_t ia = (size_t)nm * D_ + d;
    size_t ib = (size_t)(NM_ + nm) * D_ + d;
    pooledP[ia] = (wa * pooledP[ia] + wb * pooledP[ib]) * inv;
  }
}

// ---------------- tiled fp32 GEMM with split-K parts ----------------
// C[256,N] = A[256,K] @ W[N,K]^T, part ks covers k in [ks*kchunk, (ks+1)*kchunk)
// grid (N/64, 4, KS); Cp[ks][256][N]
__global__ __launch_bounds__(256) void k_gemm(const float* __restrict__ A, int K,
                                              const float* __restrict__ W,
                                              float* __restrict__ Cp, int N, int kchunk) {
  __shared__ float A_s[64][36];   // row-major, padded
  __shared__ float B_s[32][68];   // k-major, padded
  int t = threadIdx.x;
  int tx = t & 15, ty = t >> 4;
  int n0 = blockIdx.x * 64, m0 = blockIdx.y * 64;
  int k0 = blockIdx.z * kchunk;
  float4 acc[4];
#pragma unroll
  for (int u = 0; u < 4; ++u) acc[u] = make_float4(0.f, 0.f, 0.f, 0.f);

  for (int kc = 0; kc < kchunk; kc += 32) {
    __syncthreads();
#pragma unroll
    for (int it = 0; it < 2; ++it) {
      int idx = t + it * 256;
      int row = idx >> 3, c4 = idx & 7;
      float4 v = *(const float4*)&A[(size_t)(m0 + row) * K + k0 + kc + 4 * c4];
      *(float4*)&A_s[row][4 * c4] = v;
      float4 w = *(const float4*)&W[(size_t)(n0 + row) * K + k0 + kc + 4 * c4];
      B_s[4 * c4 + 0][row] = w.x;
      B_s[4 * c4 + 1][row] = w.y;
      B_s[4 * c4 + 2][row] = w.z;
      B_s[4 * c4 + 3][row] = w.w;
    }
    __syncthreads();
#pragma unroll
    for (int kk = 0; kk < 32; ++kk) {
      float4 b4 = *(const float4*)&B_s[kk][tx * 4];
      float a0 = A_s[ty * 4 + 0][kk];
      float a1 = A_s[ty * 4 + 1][kk];
      float a2 = A_s[ty * 4 + 2][kk];
      float a3 = A_s[ty * 4 + 3][kk];
      acc[0].x += a0 * b4.x; acc[0].y += a0 * b4.y; acc[0].z += a0 * b4.z; acc[0].w += a0 * b4.w;
      acc[1].x += a1 * b4.x; acc[1].y += a1 * b4.y; acc[1].z += a1 * b4.z; acc[1].w += a1 * b4.w;
      acc[2].x += a2 * b4.x; acc[2].y += a2 * b4.y; acc[2].z += a2 * b4.z; acc[2].w += a2 * b4.w;
      acc[3].x += a3 * b4.x; acc[3].y += a3 * b4.y; acc[3].z += a3 * b4.z; acc[3].w += a3 * b4.w;
    }
  }
  size_t base = (size_t)blockIdx.z * NM_ * N;
#pragma unroll
  for (int u = 0; u < 4; ++u)
    *(float4*)&Cp[base + (size_t)(m0 + ty * 4 + u) * N + n0 + tx * 4] = acc[u];
}

// ---------------- ep1: xo = sum_parts + bv ; y = LN(xo) ; one row per block ----------------
__global__ __launch_bounds__(256) void k_ep1(const float* __restrict__ xop,
                                             const float* __restrict__ bv,
                                             const float* __restrict__ gamma,
                                             const float* __restrict__ beta,
                                             float* __restrict__ xo,
                                             float* __restrict__ y) {
  __shared__ float tmpa[4], tmpb[4];
  int t = threadIdx.x, wave = t >> 6, lane = t & 63;
  int row = blockIdx.x;
  float v[3];
#pragma unroll
  for (int cc = 0; cc < 3; ++cc) {
    int j = t + 256 * cc;
    float s = bv[j];
#pragma unroll
    for (int p = 0; p < 6; ++p) s += xop[(size_t)p * NM_ * D_ + (size_t)row * D_ + j];
    v[cc] = s;
    xo[(size_t)row * D_ + j] = s;
  }
  float s = v[0] + v[1] + v[2];
  float ss = v[0] * v[0] + v[1] * v[1] + v[2] * v[2];
#pragma unroll
  for (int o = 32; o; o >>= 1) {
    s += __shfl_down(s, o);
    ss += __shfl_down(ss, o);
  }
  if (lane == 0) { tmpa[wave] = s; tmpb[wave] = ss; }
  __syncthreads();
  float mu = (tmpa[0] + tmpa[1] + tmpa[2] + tmpa[3]) * (1.f / D_);
  float var = (tmpb[0] + tmpb[1] + tmpb[2] + tmpb[3]) * (1.f / D_) - mu * mu;
  float rs = rsqrtf(var + EPS_);
#pragma unroll
  for (int cc = 0; cc < 3; ++cc) {
    int j = t + 256 * cc;
    y[(size_t)row * D_ + j] = (v[cc] - mu) * rs * gamma[j] + beta[j];
  }
}

// ---------------- ep2: h = gelu(hp0 + hp1 + b1), float4 ----------------
__global__ __launch_bounds__(256) void k_ep2(const float* __restrict__ hp,
                                             const float* __restrict__ b1,
                                             float* __restrict__ h) {
  int idx4 = blockIdx.x * 256 + threadIdx.x;
  int f = idx4 * 4;
  int col = f % H_;
  float4 p0 = *(const float4*)&hp[f];
  float4 p1 = *(const float4*)&hp[(size_t)NM_ * H_ + f];
  float4 bb = *(const float4*)&b1[col];
  float4 r;
  float vx = p0.x + p1.x + bb.x;
  float vy = p0.y + p1.y + bb.y;
  float vz = p0.z + p1.z + bb.z;
  float vw = p0.w + p1.w + bb.w;
  r.x = 0.5f * vx * (1.f + erff(vx * 0.70710678118f));
  r.y = 0.5f * vy * (1.f + erff(vy * 0.70710678118f));
  r.z = 0.5f * vz * (1.f + erff(vz * 0.70710678118f));
  r.w = 0.5f * vw * (1.f + erff(vw * 0.70710678118f));
  *(float4*)&h[f] = r;
}

// ---------------- ep3: out = sum_8_parts + b2 + xo, float4 ----------------
__global__ __launch_bounds__(256) void k_ep3(const float* __restrict__ op,
                                             const float* __restrict__ b2,
                                             const float* __restrict__ xo,
                                             float* __restrict__ out) {
  int idx4 = blockIdx.x * 256 + threadIdx.x;
  int f = idx4 * 4;
  int col = f % D_;
  float4 bb = *(const float4*)&b2[col];
  float4 xv = *(const float4*)&xo[f];
  float sx = bb.x + xv.x, sy = bb.y + xv.y, sz = bb.z + xv.z, sw = bb.w + xv.w;
#pragma unroll
  for (int p = 0; p < 8; ++p) {
    float4 pv = *(const float4*)&op[(size_t)p * NM_ * D_ + f];
    sx += pv.x; sy += pv.y; sz += pv.z; sw += pv.w;
  }
  *(float4*)&out[f] = make_float4(sx, sy, sz, sw);
}

extern "C" void kernel_launch(void* const* d_in, const int* in_sizes, int n_in,
                              void* d_out, int out_size, void* d_ws, size_t ws_size,
                              hipStream_t stream) {
  const float* x = (const float*)d_in[0];
  const float* probe = (const float*)d_in[1];
  const float* wq = (const float*)d_in[2];
  const float* bq = (const float*)d_in[3];
  const float* wk = (const float*)d_in[4];
  const float* bk = (const float*)d_in[5];
  const float* wv = (const float*)d_in[6];
  const float* bv = (const float*)d_in[7];
  const float* gamma = (const float*)d_in[8];
  const float* beta = (const float*)d_in[9];
  const float* w1 = (const float*)d_in[10];
  const float* b1 = (const float*)d_in[11];
  const float* w2 = (const float*)d_in[12];
  const float* b2 = (const float*)d_in[13];
  float* out = (float*)d_out;

  float* ws = (float*)d_ws;
  float* qkp = ws;                         // 4*768 = 3072
  float* biasp = ws + 3072;                // 4
  float* q = ws + 3104;                    // 768
  float* pooledP = ws + 4096;              // 2*256*768 = 393216 (part0 holds final)
  float2* mlP = (float2*)(ws + 397312);    // 512 float2 = 1024 floats
  float* xop = ws + 398336;                // 6*256*768 = 1179648
  float* xo = ws + 1577984;                // 196608
  float* y = ws + 1774592;                 // 196608
  float* hp = ws + 1971200;                // 2*256*3072 = 1572864
  float* h = ws + 3544064;                 // 786432
  float* op = ws + 4330496;                // 8*256*768 = 1572864
  // total 5,903,360 floats = 23.6 MB

  hipLaunchKernelGGL(k_qproj, dim3(12), dim3(256), 0, stream, probe, wq, bq, q);
  hipLaunchKernelGGL(k_kproj, dim3(3, 4), dim3(256), 0, stream, q, wk, bk, qkp, biasp);
  hipLaunchKernelGGL(k_attnpool, dim3(NM_, 2), dim3(256), 0, stream, x, qkp, biasp, pooledP, mlP);
  hipLaunchKernelGGL(k_merge, dim3(NM_), dim3(256), 0, stream, pooledP, mlP);
  // xo_acc = pooled @ wv.T : K=768 split 6 (kchunk 128)
  hipLaunchKernelGGL(k_gemm, dim3(12, 4, 6), dim3(256), 0, stream, pooledP, D_, wv, xop, D_, 128);
  hipLaunchKernelGGL(k_ep1, dim3(NM_), dim3(256), 0, stream, xop, bv, gamma, beta, xo, y);
  // hpre = y @ w1.T : K=768 split 2 (kchunk 384)
  hipLaunchKernelGGL(k_gemm, dim3(48, 4, 2), dim3(256), 0, stream, y, D_, w1, hp, H_, 384);
  hipLaunchKernelGGL(k_ep2, dim3(768), dim3(256), 0, stream, hp, b1, h);
  // outpre = h @ w2.T : K=3072 split 8 (kchunk 384)
  hipLaunchKernelGGL(k_gemm, dim3(12, 4, 8), dim3(256), 0, stream, h, H_, w2, op, D_, 384);
  hipLaunchKernelGGL(k_ep3, dim3(192), dim3(256), 0, stream, op, b2, xo, out);
}